// Round 1
// baseline (142.150 us; speedup 1.0000x reference)
//
#include <hip/hip_runtime.h>

// Pipeline (see reference):
//   bins = clip(|x|,0,20)  -> one-hot conv == per-pixel gather of w0[o, bin(tap), k]
//   stage1 kernel: fused layer0 (dil-8 3x3, BN0 folded) + layer1 (1x1 64->4, BN1 folded)
//                  + block rearrange (x qtable) + 1x1 512->3 (+b2, BN2 folded)
//                  -> z [8,3,64,64] f32 in d_ws (393,216 bytes)
//   stage2 kernel: bilinear x8 upsample (half-pixel centers, edge clamp) -> d_out

#define NB_BINS 22  // 21 real bins + sentinel bin 21 for out-of-bounds taps

__global__ __launch_bounds__(256, 2) void dct_stage1(
    const int* __restrict__ xin,      // [8,1,512,512] int32
    const float* __restrict__ qtable, // [8,8,8]
    const float* __restrict__ w0,     // [64,21,3,3]
    const float* __restrict__ b0,     // [64]
    const float* __restrict__ s0,     // [64]
    const float* __restrict__ t0,     // [64]
    const float* __restrict__ w1,     // [4,64]
    const float* __restrict__ s1,     // [4]
    const float* __restrict__ t1,     // [4]
    const float* __restrict__ w2,     // [3,512]
    const float* __restrict__ b2,     // [3]
    const float* __restrict__ s2,     // [3]
    const float* __restrict__ t2,     // [3]
    float* __restrict__ zout)         // [8,3,64,64]
{
    // tab[o][k][bin] = s0[o]*w0[o][bin][ky][kx] + g0[o]/9   (bin < 21)
    //               = g0[o]/9                               (bin == 21, OOB tap)
    // where g0 = s0*b0 + t0.  Sum over the 9 taps then equals s0*conv + g0 exactly.
    __shared__ float tab[64 * 9 * NB_BINS];   // 50688 B
    __shared__ float w1s[64 * 4];             // s1-folded w1, layout [o][c]

    const int tid = threadIdx.x;
    const int bid = blockIdx.x;       // 512 workgroups: (b, hb)
    const int b   = bid >> 6;
    const int hb  = bid & 63;

    for (int t = tid; t < 64 * 9 * NB_BINS; t += 256) {
        int o   = t / (9 * NB_BINS);
        int rem = t - o * (9 * NB_BINS);
        int k   = rem / NB_BINS;
        int bin = rem - k * NB_BINS;
        float g0 = fmaf(s0[o], b0[o], t0[o]) * (1.0f / 9.0f);
        float val = g0;
        if (bin < 21) {
            int ky = k / 3, kx = k - ky * 3;
            val = fmaf(s0[o], w0[((o * 21 + bin) * 3 + ky) * 3 + kx], g0);
        }
        tab[t] = val;
    }
    for (int t = tid; t < 256; t += 256) {
        int o = t >> 2, c = t & 3;
        w1s[t] = s1[c] * w1[c * 64 + o];
    }
    __syncthreads();

    const int lane = tid & 63;
    const int wave = tid >> 6;
    const int i = lane >> 3;          // row within 8x8 block
    const int j = lane & 7;           // col within 8x8 block

    // Per-lane constants for the block-rearrange + 512->3 conv.
    // z channel index = c*64 + i*8 + j  (= c*64 + lane); channels 256.. get *qtable.
    const float q = qtable[b * 64 + lane];
    float A[3][4], Bq[3][4];
#pragma unroll
    for (int oc = 0; oc < 3; ++oc) {
        float s = s2[oc];
#pragma unroll
        for (int c = 0; c < 4; ++c) {
            A[oc][c]  = s * w2[oc * 512 + c * 64 + lane];
            Bq[oc][c] = s * w2[oc * 512 + 256 + c * 64 + lane];
        }
    }
    const float zc0 = fmaf(s2[0], b2[0], t2[0]);
    const float zc1 = fmaf(s2[1], b2[1], t2[1]);
    const float zc2 = fmaf(s2[2], b2[2], t2[2]);
    const float t1r0 = t1[0], t1r1 = t1[1], t1r2 = t1[2], t1r3 = t1[3];

    const int y = hb * 8 + i;

    for (int t = 0; t < 16; ++t) {
        const int wb = wave * 16 + t;     // 4 waves x 16 -> 64 blocks per strip
        const int xc = wb * 8 + j;

        // 9 tap bins -> LDS offsets (k*22 + bin)
        int offs[9];
#pragma unroll
        for (int ky = 0; ky < 3; ++ky) {
#pragma unroll
            for (int kx = 0; kx < 3; ++kx) {
                int yy = y + (ky - 1) * 8;
                int xx = xc + (kx - 1) * 8;
                int bin = 21;
                if ((unsigned)yy < 512u && (unsigned)xx < 512u) {
                    int v = xin[(b * 512 + yy) * 512 + xx];
                    v = v < 0 ? -v : v;
                    bin = v > 20 ? 20 : v;
                }
                offs[ky * 3 + kx] = (ky * 3 + kx) * NB_BINS + bin;
            }
        }

        float u0 = t1r0, u1 = t1r1, u2 = t1r2, u3 = t1r3;
#pragma unroll 8
        for (int o = 0; o < 64; ++o) {
            const float* tb = &tab[o * (9 * NB_BINS)];
            float acc = tb[offs[0]] + tb[offs[1]] + tb[offs[2]]
                      + tb[offs[3]] + tb[offs[4]] + tb[offs[5]]
                      + tb[offs[6]] + tb[offs[7]] + tb[offs[8]];
            float v = fmaxf(acc, 0.0f);   // relu(s0*conv0 + s0*b0 + t0)
            const float4 w = *(const float4*)&w1s[o * 4];
            u0 = fmaf(w.x, v, u0);
            u1 = fmaf(w.y, v, u1);
            u2 = fmaf(w.z, v, u2);
            u3 = fmaf(w.w, v, u3);
        }
        u0 = fmaxf(u0, 0.0f);  // relu(s1*conv1 + t1)
        u1 = fmaxf(u1, 0.0f);
        u2 = fmaxf(u2, 0.0f);
        u3 = fmaxf(u3, 0.0f);
        const float uq0 = u0 * q, uq1 = u1 * q, uq2 = u2 * q, uq3 = u3 * q;

        float p[3];
#pragma unroll
        for (int oc = 0; oc < 3; ++oc) {
            p[oc] = A[oc][0] * u0 + A[oc][1] * u1 + A[oc][2] * u2 + A[oc][3] * u3
                  + Bq[oc][0] * uq0 + Bq[oc][1] * uq1 + Bq[oc][2] * uq2 + Bq[oc][3] * uq3;
        }
#pragma unroll
        for (int m = 1; m < 64; m <<= 1) {
            p[0] += __shfl_xor(p[0], m);
            p[1] += __shfl_xor(p[1], m);
            p[2] += __shfl_xor(p[2], m);
        }
        if (lane == 0) {
            zout[((b * 3 + 0) * 64 + hb) * 64 + wb] = p[0] + zc0;
            zout[((b * 3 + 1) * 64 + hb) * 64 + wb] = p[1] + zc1;
            zout[((b * 3 + 2) * 64 + hb) * 64 + wb] = p[2] + zc2;
        }
    }
}

// Bilinear x8 upsample, half-pixel centers (align_corners=False), edge clamp.
// src = (dst + 0.5)/8 - 0.5; weights periodic with dst%8.
__global__ __launch_bounds__(256) void upsample8(
    const float* __restrict__ z,   // [8,3,64,64]
    float* __restrict__ out)       // [8,3,512,512]
{
    const int idx = blockIdx.x * 256 + threadIdx.x;   // 1,572,864 threads, 4 outs each
    const int x4    = idx & 127;
    const int rest  = idx >> 7;
    const int yy    = rest & 511;
    const int plane = rest >> 9;          // b*3 + oc, 0..23

    const float* zp = z + plane * 4096;

    const int yb = yy >> 3, r = yy & 7;
    int y0; float fy;
    if (r < 4) { y0 = yb - 1; fy = (2 * r + 9) * (1.0f / 16.0f); }
    else       { y0 = yb;     fy = (2 * r - 7) * (1.0f / 16.0f); }
    int y1 = y0 + 1;
    y0 = y0 < 0 ? 0 : y0;
    y1 = y1 > 63 ? 63 : y1;
    const float* row0 = zp + y0 * 64;
    const float* row1 = zp + y1 * 64;

    float4 res;
    float* rp = (float*)&res;
#pragma unroll
    for (int t = 0; t < 4; ++t) {
        int x = x4 * 4 + t;
        int xb = x >> 3, rr = x & 7;
        int x0; float fx;
        if (rr < 4) { x0 = xb - 1; fx = (2 * rr + 9) * (1.0f / 16.0f); }
        else        { x0 = xb;     fx = (2 * rr - 7) * (1.0f / 16.0f); }
        int x1 = x0 + 1;
        x0 = x0 < 0 ? 0 : x0;
        x1 = x1 > 63 ? 63 : x1;
        float a0 = row0[x0], a1 = row0[x1];
        float b0v = row1[x0], b1v = row1[x1];
        float v0 = a0 + fx * (a1 - a0);
        float v1 = b0v + fx * (b1v - b0v);
        rp[t] = v0 + fy * (v1 - v0);
    }
    *(float4*)&out[idx * 4] = res;
}

extern "C" void kernel_launch(void* const* d_in, const int* in_sizes, int n_in,
                              void* d_out, int out_size, void* d_ws, size_t ws_size,
                              hipStream_t stream) {
    const int*   x      = (const int*)d_in[0];
    const float* qtable = (const float*)d_in[1];
    const float* w0     = (const float*)d_in[2];
    const float* b0     = (const float*)d_in[3];
    const float* s0     = (const float*)d_in[4];
    const float* t0     = (const float*)d_in[5];
    const float* w1     = (const float*)d_in[6];
    const float* s1     = (const float*)d_in[7];
    const float* t1     = (const float*)d_in[8];
    const float* w2     = (const float*)d_in[9];
    const float* b2     = (const float*)d_in[10];
    const float* s2     = (const float*)d_in[11];
    const float* t2     = (const float*)d_in[12];

    float* zbuf = (float*)d_ws;            // needs 8*3*64*64*4 = 393,216 B
    float* out  = (float*)d_out;

    dct_stage1<<<512, 256, 0, stream>>>(x, qtable, w0, b0, s0, t0,
                                        w1, s1, t1, w2, b2, s2, t2, zbuf);
    upsample8<<<6144, 256, 0, stream>>>(zbuf, out);
}